// Round 7
// baseline (173.766 us; speedup 1.0000x reference)
//
#include <hip/hip_runtime.h>
#include <hip/hip_bf16.h>
#include <math.h>

// HMM forward (logZ), K=64 tags, V=50000, D=128, BATCH=8192, L=126.
// MFMA formulation: alpha_next[16 sent][64 tag] = (alpha x T') .* e_raw[word],
// T' = softmax(WA) with 65536/sumexp[col] folded in (BOS/EOS cols = 0).
// k_fwd runs TWO independent 16-sentence chains per wave (ILP against the
// serial-latency bound seen in r5/r6: 1100 cyc/step at 5% occupancy).
//
// ws layout:
//   [0, 6,400,000)        btn_bf[v][k]  bf16  raw exp(logit)
//   [6,400,000, +16384)   A[i][j]       f32   softmax(WA, col BOS=-inf)+EPS
//   [6,416,384, +256)     sumexp[k]     f32
//   [6,416,640, +200704)  partial[k][784] f32 per-block column sums

#define KT 64
#define VV 50000
#define DD 128
#define BOS_T 62
#define EOS_T 63
#define LLEN 126
#define EPSF 1e-45f
#define SCALE_F 65536.0f
#define LOG_TOTAL_SCALE (2016.0f * 0.6931471805599453f)
#define PITCH 68          // f32 row pitch of LDS alpha tile
#define NBLK 782          // k_emit grid
#define PBLK 784          // padded partial row

#define BTN_OFF   0
#define A_OFF     6400000
#define SUM_OFF   6416384
#define PART_OFF  6416640

typedef short short8 __attribute__((ext_vector_type(8)));
typedef float f32x4  __attribute__((ext_vector_type(4)));

union U8 { short8 v; unsigned u[4]; short s[8]; };

static __device__ inline unsigned short f2bf_u(float x) {
    __hip_bfloat16 h = __float2bfloat16(x);
    return *reinterpret_cast<unsigned short*>(&h);
}
static __device__ inline short f2bf(float x) { return (short)f2bf_u(x); }

// hot-path packed f32->bf16x2
#if __has_builtin(__builtin_amdgcn_cvt_pk_bf16_f32)
typedef __bf16 bf16x2 __attribute__((ext_vector_type(2)));
static __device__ inline unsigned pk2(float a, float b) {
    bf16x2 r = __builtin_amdgcn_cvt_pk_bf16_f32(a, b);
    return *reinterpret_cast<unsigned*>(&r);
}
#else
static __device__ inline unsigned pk2(float a, float b) {
    union { float f; unsigned u; } ua, ub;
    ua.f = a; ub.f = b;
    return ((ua.u + 0x8000u) >> 16) | ((ub.u + 0x8000u) & 0xFFFF0000u);
}
#endif
static __device__ inline float lo16(unsigned u) { union { unsigned i; float f; } c; c.i = u << 16;        return c.f; }
static __device__ inline float hi16(unsigned u) { union { unsigned i; float f; } c; c.i = u & 0xffff0000u; return c.f; }

// ---------------------------------------------------------------- btn_bf[v][k] = bf16(exp(E[v].ThetaB[k]))  (MFMA GEMM)
__global__ __launch_bounds__(256) void k_emit(const float* __restrict__ ThetaB,
                                              const float* __restrict__ E,
                                              unsigned short* __restrict__ btn_bf,
                                              float* __restrict__ partial) {
    __shared__ float red[4][KT];
    int t    = threadIdx.x;
    int lane = t & 63;
    int w    = t >> 6;
    int n    = lane & 15;
    int q    = lane >> 4;
    int v0   = (blockIdx.x * 4 + w) * 16;

    // E rows are the cold HBM traffic — issue early.
    int rowE = v0 + n; rowE = rowE < VV ? rowE : VV - 1;
    float4 ex[4][2];
#pragma unroll
    for (int kt = 0; kt < 4; ++kt) {
        const float* p = E + (size_t)rowE * DD + kt * 32 + q * 8;
        ex[kt][0] = *(const float4*)p;
        ex[kt][1] = *(const float4*)(p + 4);
    }

    short8 Bf[4][4];
#pragma unroll
    for (int kt = 0; kt < 4; ++kt)
#pragma unroll
        for (int nt = 0; nt < 4; ++nt) {
            const float* p = ThetaB + (nt * 16 + n) * DD + kt * 32 + q * 8;
            float4 x = *(const float4*)p;
            float4 y = *(const float4*)(p + 4);
            U8 f;
            f.u[0] = pk2(x.x, x.y); f.u[1] = pk2(x.z, x.w);
            f.u[2] = pk2(y.x, y.y); f.u[3] = pk2(y.z, y.w);
            Bf[kt][nt] = f.v;
        }

    short8 Ae[4];
#pragma unroll
    for (int kt = 0; kt < 4; ++kt) {
        U8 f;
        f.u[0] = pk2(ex[kt][0].x, ex[kt][0].y); f.u[1] = pk2(ex[kt][0].z, ex[kt][0].w);
        f.u[2] = pk2(ex[kt][1].x, ex[kt][1].y); f.u[3] = pk2(ex[kt][1].z, ex[kt][1].w);
        Ae[kt] = f.v;
    }

#pragma unroll
    for (int nt = 0; nt < 4; ++nt) {
        f32x4 C = {0.f, 0.f, 0.f, 0.f};
#pragma unroll
        for (int kt = 0; kt < 4; ++kt)
            C = __builtin_amdgcn_mfma_f32_16x16x32_bf16(Ae[kt], Bf[kt][nt], C, 0, 0, 0);
        float ps = 0.0f;
#pragma unroll
        for (int r = 0; r < 4; ++r) {
            int row = v0 + 4 * q + r;
            float e = __expf(C[r]);
            if (row < VV) {
                btn_bf[(size_t)row * KT + nt * 16 + n] = f2bf_u(e);
                ps += e;
            }
        }
        ps += __shfl_xor(ps, 16, 64);
        ps += __shfl_xor(ps, 32, 64);
        if (q == 0) red[w][nt * 16 + n] = ps;
    }
    __syncthreads();
    if (w == 0) {
        float s = red[0][lane] + red[1][lane] + red[2][lane] + red[3][lane];
        partial[lane * PBLK + blockIdx.x] = s;
    }
}

// ---------------------------------------------------------------- sumexp[k] = sum partial[k][:]; A row k = softmax(WA row k)
__global__ __launch_bounds__(256) void k_sumA(const float* __restrict__ partial,
                                              const float* __restrict__ WA,
                                              float* __restrict__ sumexp,
                                              float* __restrict__ A) {
    __shared__ float r[4];
    int k = blockIdx.x;
    int t = threadIdx.x;
    float s = 0.0f;
    for (int i = t; i < NBLK; i += 256) s += partial[k * PBLK + i];
#pragma unroll
    for (int off = 32; off > 0; off >>= 1) s += __shfl_xor(s, off, 64);
    if ((t & 63) == 0) r[t >> 6] = s;
    __syncthreads();
    if (t == 0) sumexp[k] = r[0] + r[1] + r[2] + r[3];
    // fold former k_prepA: wave 0 computes softmax of WA row k
    if (t < 64) {
        float wv = WA[k * KT + t];
        float e = (t == BOS_T) ? 0.0f : __expf(wv);
        float se = e;
#pragma unroll
        for (int off = 32; off > 0; off >>= 1) se += __shfl_xor(se, off, 64);
        A[k * KT + t] = e / se + EPSF;
    }
}

// ---------------------------------------------------------------- forward scan: 1 wave = 2 x 16 sentences, MFMA
__global__ __launch_bounds__(64) void k_fwd(const int* __restrict__ words,
                                            const unsigned short* __restrict__ btn_bf,
                                            const float* __restrict__ A,
                                            const float* __restrict__ sumexp,
                                            float* __restrict__ out) {
    __shared__ __attribute__((aligned(16))) float sh[2][16 * PITCH];
    int lane = threadIdx.x & 63;
    int n    = lane & 15;
    int q    = lane >> 4;
    int b0   = blockIdx.x * 32;

    // rs[j] = 65536/sumexp[j], BOS/EOS -> 0 (k_norm folded into T' columns)
    float rs4[4];
#pragma unroll
    for (int nt = 0; nt < 4; ++nt) {
        int col = nt * 16 + n;
        float s = sumexp[col];
        rs4[nt] = (col == BOS_T || col == EOS_T) ? 0.0f : (SCALE_F / s);
    }

    // B-frags of scaled transition T' (shared by both chains)
    short8 Bf[2][4];
#pragma unroll
    for (int kt = 0; kt < 2; ++kt)
#pragma unroll
        for (int nt = 0; nt < 4; ++nt) {
            U8 f;
#pragma unroll
            for (int j = 0; j < 8; ++j)
                f.s[j] = f2bf(A[(kt * 32 + q * 8 + j) * KT + nt * 16 + n] * rs4[nt]);
            Bf[kt][nt] = f.v;
        }

    // alpha frags per chain: one-hot at tag 62 -> kt=1, q=3, slot 6
    short8 Af[2][2];
    {
        U8 a0, a1;
#pragma unroll
        for (int j = 0; j < 4; ++j) { a0.u[j] = 0; a1.u[j] = 0; }
        if (q == 3) a1.s[6] = (short)0x3F80;   // bf16(1.0)
#pragma unroll
        for (int c = 0; c < 2; ++c) { Af[c][0] = a0.v; Af[c][1] = a1.v; }
    }

    const int* wrow[2] = { words + (size_t)(b0 + n) * LLEN,
                           words + (size_t)(b0 + 16 + n) * LLEN };

    // 3-deep emission prefetch per chain
    uint4 ep[2][3][2];
    int wn[2];
#pragma unroll
    for (int c = 0; c < 2; ++c) {
#pragma unroll
        for (int d = 0; d < 3; ++d) {
            int wd = wrow[c][d];
            ep[c][d][0] = *(const uint4*)(btn_bf + (size_t)wd * KT + q * 8);
            ep[c][d][1] = *(const uint4*)(btn_bf + (size_t)wd * KT + 32 + q * 8);
        }
        wn[c] = wrow[c][3];
    }

    for (int l = 0; l < LLEN; ++l) {
        // issue step-(l+3) prefetches first: no dependents for 3 iterations
        uint4 e3[2][2];
#pragma unroll
        for (int c = 0; c < 2; ++c) {
            e3[c][0] = *(const uint4*)(btn_bf + (size_t)wn[c] * KT + q * 8);
            e3[c][1] = *(const uint4*)(btn_bf + (size_t)wn[c] * KT + 32 + q * 8);
            int wi = l + 4; wi = wi < LLEN ? wi : LLEN - 1;
            wn[c] = wrow[c][wi];
        }

        // both chains' MFMAs (independent -> interleaved issue)
        f32x4 C[2][4];
#pragma unroll
        for (int c = 0; c < 2; ++c)
#pragma unroll
            for (int nt = 0; nt < 4; ++nt) {
                f32x4 acc = {0.f, 0.f, 0.f, 0.f};
                acc = __builtin_amdgcn_mfma_f32_16x16x32_bf16(Af[c][0], Bf[0][nt], acc, 0, 0, 0);
                acc = __builtin_amdgcn_mfma_f32_16x16x32_bf16(Af[c][1], Bf[1][nt], acc, 0, 0, 0);
                C[c][nt] = acc;
            }

        // C -> LDS tiles (m = 4q+r, k = nt*16+n), single drain, then reads
#pragma unroll
        for (int c = 0; c < 2; ++c)
#pragma unroll
            for (int nt = 0; nt < 4; ++nt)
#pragma unroll
                for (int r = 0; r < 4; ++r)
                    sh[c][(4 * q + r) * PITCH + nt * 16 + n] = C[c][nt][r];
        asm volatile("s_waitcnt lgkmcnt(0)" ::: "memory");

#pragma unroll
        for (int c = 0; c < 2; ++c) {
            {
                const float* p = sh[c] + n * PITCH + q * 8;
                float4 lo = *(const float4*)p;
                float4 hi = *(const float4*)(p + 4);
                uint4 e = ep[c][0][0];
                U8 f;
                f.u[0] = pk2(lo.x * lo16(e.x), lo.y * hi16(e.x));
                f.u[1] = pk2(lo.z * lo16(e.y), lo.w * hi16(e.y));
                f.u[2] = pk2(hi.x * lo16(e.z), hi.y * hi16(e.z));
                f.u[3] = pk2(hi.z * lo16(e.w), hi.w * hi16(e.w));
                Af[c][0] = f.v;
            }
            {
                const float* p = sh[c] + n * PITCH + 32 + q * 8;
                float4 lo = *(const float4*)p;
                float4 hi = *(const float4*)(p + 4);
                uint4 e = ep[c][0][1];
                U8 f;
                f.u[0] = pk2(lo.x * lo16(e.x), lo.y * hi16(e.x));
                f.u[1] = pk2(lo.z * lo16(e.y), lo.w * hi16(e.y));
                f.u[2] = pk2(hi.x * lo16(e.z), hi.y * hi16(e.z));
                f.u[3] = pk2(hi.z * lo16(e.w), hi.w * hi16(e.w));
                Af[c][1] = f.v;
            }
#pragma unroll
            for (int k2 = 0; k2 < 2; ++k2) {
                ep[c][0][k2] = ep[c][1][k2];
                ep[c][1][k2] = ep[c][2][k2];
                ep[c][2][k2] = e3[c][k2];
            }
        }
    }

    // final: logZ = log(sum_j alpha[j] * A[j][EOS]) - total scale
    short8 Bfin[2];
#pragma unroll
    for (int kt = 0; kt < 2; ++kt) {
        U8 f;
#pragma unroll
        for (int j = 0; j < 8; ++j)
            f.s[j] = (n == 0) ? f2bf(A[(kt * 32 + q * 8 + j) * KT + EOS_T]) : (short)0;
        Bfin[kt] = f.v;
    }
#pragma unroll
    for (int c = 0; c < 2; ++c) {
        f32x4 Cf = {0.f, 0.f, 0.f, 0.f};
        Cf = __builtin_amdgcn_mfma_f32_16x16x32_bf16(Af[c][0], Bfin[0], Cf, 0, 0, 0);
        Cf = __builtin_amdgcn_mfma_f32_16x16x32_bf16(Af[c][1], Bfin[1], Cf, 0, 0, 0);
        if (n == 0) {
#pragma unroll
            for (int r = 0; r < 4; ++r)
                out[b0 + 16 * c + 4 * q + r] = logf(Cf[r]) - LOG_TOTAL_SCALE;
        }
    }
}

extern "C" void kernel_launch(void* const* d_in, const int* in_sizes, int n_in,
                              void* d_out, int out_size, void* d_ws, size_t ws_size,
                              hipStream_t stream) {
    const int*   words  = (const int*)d_in[0];     // [8192,126]
    const float* ThetaB = (const float*)d_in[1];   // [64,128]
    const float* WA     = (const float*)d_in[2];   // [64,64]
    const float* E      = (const float*)d_in[3];   // [50000,128]
    float* out = (float*)d_out;                    // [8192]

    char* ws = (char*)d_ws;
    unsigned short* btn_bf = (unsigned short*)(ws + BTN_OFF);
    float* A       = (float*)(ws + A_OFF);
    float* sumexp  = (float*)(ws + SUM_OFF);
    float* partial = (float*)(ws + PART_OFF);

    k_emit<<<NBLK, 256, 0, stream>>>(ThetaB, E, btn_bf, partial);
    k_sumA<<<KT, 256, 0, stream>>>(partial, WA, sumexp, A);
    k_fwd<<<8192 / 32, 64, 0, stream>>>(words, btn_bf, A, sumexp, out);
}

// Round 8
// 160.902 us; speedup vs baseline: 1.0799x; 1.0799x over previous
//
#include <hip/hip_runtime.h>
#include <hip/hip_bf16.h>
#include <math.h>

// HMM forward (logZ), K=64 tags, V=50000, D=128, BATCH=8192, L=126.
// Transposed MFMA recurrence: beta = alpha^T;  beta_next = (T'^T x beta) .* e.
// Tag positions are relabeled so the MFMA C-layout (col=lane&15,row=q*4+reg)
// maps to the next step's B-operand layout (n=lane&15,k=q*8+j) by PURE
// IN-LANE REGISTER RENAMING:  B_kt slot j  <-  C[2kt+(j>>2)][j&3].
// No LDS, no shuffles, no waitcnt drain in the 126-step loop (r5-r7 showed
// the LDS round-trip dominated at ~780-1100 cyc/step).
// Permutation lives only in the A-operand (T'^T) construction:
//   tag at C-position (mt, m) = 32*(mt>>1) + 8*(m>>2) + 4*(mt&1) + (m&3).
//
// ws layout:
//   [0, 6,400,000)        btn_bf[v][k]  bf16  raw exp(logit), natural tag order
//   [6,400,000, +16384)   A[i][j]       f32   softmax(WA, col BOS=-inf)+EPS
//   [6,416,384, +256)     sumexp[k]     f32
//   [6,416,640, +200704)  partial[k][784] f32 per-block column sums

#define KT 64
#define VV 50000
#define DD 128
#define BOS_T 62
#define EOS_T 63
#define LLEN 126
#define EPSF 1e-45f
#define SCALE_F 65536.0f
#define LOG_TOTAL_SCALE (2016.0f * 0.6931471805599453f)
#define NBLK 782          // k_emit grid
#define PBLK 784          // padded partial row

#define BTN_OFF   0
#define A_OFF     6400000
#define SUM_OFF   6416384
#define PART_OFF  6416640

typedef short short8 __attribute__((ext_vector_type(8)));
typedef float f32x4  __attribute__((ext_vector_type(4)));

union U8 { short8 v; unsigned u[4]; short s[8]; };

static __device__ inline unsigned short f2bf_u(float x) {
    __hip_bfloat16 h = __float2bfloat16(x);
    return *reinterpret_cast<unsigned short*>(&h);
}
static __device__ inline short f2bf(float x) { return (short)f2bf_u(x); }

#if __has_builtin(__builtin_amdgcn_cvt_pk_bf16_f32)
typedef __bf16 bf16x2 __attribute__((ext_vector_type(2)));
static __device__ inline unsigned pk2(float a, float b) {
    bf16x2 r = __builtin_amdgcn_cvt_pk_bf16_f32(a, b);
    return *reinterpret_cast<unsigned*>(&r);
}
#else
static __device__ inline unsigned pk2(float a, float b) {
    union { float f; unsigned u; } ua, ub;
    ua.f = a; ub.f = b;
    return ((ua.u + 0x8000u) >> 16) | ((ub.u + 0x8000u) & 0xFFFF0000u);
}
#endif
static __device__ inline float lo16(unsigned u) { union { unsigned i; float f; } c; c.i = u << 16;        return c.f; }
static __device__ inline float hi16(unsigned u) { union { unsigned i; float f; } c; c.i = u & 0xffff0000u; return c.f; }

// ---------------------------------------------------------------- btn_bf[v][k] = bf16(exp(E[v].ThetaB[k]))  (MFMA GEMM)
__global__ __launch_bounds__(256) void k_emit(const float* __restrict__ ThetaB,
                                              const float* __restrict__ E,
                                              unsigned short* __restrict__ btn_bf,
                                              float* __restrict__ partial) {
    __shared__ float red[4][KT];
    int t    = threadIdx.x;
    int lane = t & 63;
    int w    = t >> 6;
    int n    = lane & 15;
    int q    = lane >> 4;
    int v0   = (blockIdx.x * 4 + w) * 16;

    // E rows are the cold HBM traffic — issue early.
    int rowE = v0 + n; rowE = rowE < VV ? rowE : VV - 1;
    float4 ex[4][2];
#pragma unroll
    for (int kt = 0; kt < 4; ++kt) {
        const float* p = E + (size_t)rowE * DD + kt * 32 + q * 8;
        ex[kt][0] = *(const float4*)p;
        ex[kt][1] = *(const float4*)(p + 4);
    }

    short8 Bf[4][4];
#pragma unroll
    for (int kt = 0; kt < 4; ++kt)
#pragma unroll
        for (int nt = 0; nt < 4; ++nt) {
            const float* p = ThetaB + (nt * 16 + n) * DD + kt * 32 + q * 8;
            float4 x = *(const float4*)p;
            float4 y = *(const float4*)(p + 4);
            U8 f;
            f.u[0] = pk2(x.x, x.y); f.u[1] = pk2(x.z, x.w);
            f.u[2] = pk2(y.x, y.y); f.u[3] = pk2(y.z, y.w);
            Bf[kt][nt] = f.v;
        }

    short8 Ae[4];
#pragma unroll
    for (int kt = 0; kt < 4; ++kt) {
        U8 f;
        f.u[0] = pk2(ex[kt][0].x, ex[kt][0].y); f.u[1] = pk2(ex[kt][0].z, ex[kt][0].w);
        f.u[2] = pk2(ex[kt][1].x, ex[kt][1].y); f.u[3] = pk2(ex[kt][1].z, ex[kt][1].w);
        Ae[kt] = f.v;
    }

#pragma unroll
    for (int nt = 0; nt < 4; ++nt) {
        f32x4 C = {0.f, 0.f, 0.f, 0.f};
#pragma unroll
        for (int kt = 0; kt < 4; ++kt)
            C = __builtin_amdgcn_mfma_f32_16x16x32_bf16(Ae[kt], Bf[kt][nt], C, 0, 0, 0);
        float ps = 0.0f;
#pragma unroll
        for (int r = 0; r < 4; ++r) {
            int row = v0 + 4 * q + r;
            float e = __expf(C[r]);
            if (row < VV) {
                btn_bf[(size_t)row * KT + nt * 16 + n] = f2bf_u(e);
                ps += e;
            }
        }
        ps += __shfl_xor(ps, 16, 64);
        ps += __shfl_xor(ps, 32, 64);
        if (q == 0) red[w][nt * 16 + n] = ps;
    }
    __syncthreads();
    if (w == 0) {
        float s = red[0][lane] + red[1][lane] + red[2][lane] + red[3][lane];
        partial[lane * PBLK + blockIdx.x] = s;
    }
}

// ---------------------------------------------------------------- sumexp[k] = sum partial[k][:]; A row k = softmax(WA row k)
__global__ __launch_bounds__(256) void k_sumA(const float* __restrict__ partial,
                                              const float* __restrict__ WA,
                                              float* __restrict__ sumexp,
                                              float* __restrict__ A) {
    __shared__ float r[4];
    int k = blockIdx.x;
    int t = threadIdx.x;
    float s = 0.0f;
    for (int i = t; i < NBLK; i += 256) s += partial[k * PBLK + i];
#pragma unroll
    for (int off = 32; off > 0; off >>= 1) s += __shfl_xor(s, off, 64);
    if ((t & 63) == 0) r[t >> 6] = s;
    __syncthreads();
    if (t == 0) sumexp[k] = r[0] + r[1] + r[2] + r[3];
    if (t < 64) {
        float wv = WA[k * KT + t];
        float e = (t == BOS_T) ? 0.0f : __expf(wv);
        float se = e;
#pragma unroll
        for (int off = 32; off > 0; off >>= 1) se += __shfl_xor(se, off, 64);
        A[k * KT + t] = e / se + EPSF;
    }
}

// ---------------------------------------------------------------- forward scan: 1 wave = 16 sentences, zero-LDS MFMA
__global__ __launch_bounds__(64) void k_fwd(const int* __restrict__ words,
                                            const unsigned short* __restrict__ btn_bf,
                                            const float* __restrict__ A,
                                            const float* __restrict__ sumexp,
                                            float* __restrict__ out) {
    int lane = threadIdx.x & 63;
    int n    = lane & 15;     // sentence col (B/C side); row m (A side)
    int qA   = lane >> 4;
    int b0   = blockIdx.x * 16;

    // A-operand frags of scaled T'^T; tag at C-position (mt, m):
    //   tagn = 32*(mt>>1) + 8*(m>>2) + 4*(mt&1) + (m&3)
    short8 Af[2][4];
#pragma unroll
    for (int mt = 0; mt < 4; ++mt) {
        int tagn = 32 * (mt >> 1) + 8 * (n >> 2) + 4 * (mt & 1) + (n & 3);
        float s = sumexp[tagn];
        float rsn = (tagn == BOS_T || tagn == EOS_T) ? 0.0f : (SCALE_F / s);
#pragma unroll
        for (int kt = 0; kt < 2; ++kt) {
            U8 f;
#pragma unroll
            for (int j = 0; j < 8; ++j)
                f.s[j] = f2bf(A[(kt * 32 + qA * 8 + j) * KT + tagn] * rsn);
            Af[kt][mt] = f.v;
        }
    }

    // beta_0 one-hot at tag 62 = B-position (kt=1, q=3, j=6)
    short8 B0, B1;
    {
        U8 z; z.u[0] = z.u[1] = z.u[2] = z.u[3] = 0;
        B0 = z.v;
        U8 o; o.u[0] = o.u[1] = o.u[2] = o.u[3] = 0;
        if (qA == 3) o.s[6] = (short)0x3F80;   // bf16(1.0)
        B1 = o.v;
    }

    const int* wrow = words + (size_t)(b0 + n) * LLEN;

    // 6-deep emission prefetch ring (full unroll -> register renamed)
    uint4 ep0[6], ep1[6];
#pragma unroll
    for (int d = 0; d < 6; ++d) {
        int wd = wrow[d];
        ep0[d] = *(const uint4*)(btn_bf + (size_t)wd * KT + qA * 8);
        ep1[d] = *(const uint4*)(btn_bf + (size_t)wd * KT + 32 + qA * 8);
    }
    int w1 = wrow[6], w2 = wrow[7];   // 2-deep word pipeline

    for (int l6 = 0; l6 < LLEN; l6 += 6) {
#pragma unroll
        for (int u = 0; u < 6; ++u) {
            int g = l6 + u;
            uint4 e0 = ep0[u], e1 = ep1[u];
            // refill slot u with step g+6's emission row
            {
                int wg = w1; w1 = w2;
                int wi = g + 8; wi = wi < LLEN ? wi : LLEN - 1;
                w2 = wrow[wi];
                ep0[u] = *(const uint4*)(btn_bf + (size_t)wg * KT + qA * 8);
                ep1[u] = *(const uint4*)(btn_bf + (size_t)wg * KT + 32 + qA * 8);
            }
            // C[mt] = Af[0][mt] x B0 + Af[1][mt] x B1
            f32x4 C[4];
#pragma unroll
            for (int mt = 0; mt < 4; ++mt) {
                f32x4 acc = {0.f, 0.f, 0.f, 0.f};
                acc = __builtin_amdgcn_mfma_f32_16x16x32_bf16(Af[0][mt], B0, acc, 0, 0, 0);
                acc = __builtin_amdgcn_mfma_f32_16x16x32_bf16(Af[1][mt], B1, acc, 0, 0, 0);
                C[mt] = acc;
            }
            // next B-frags: kt slot j <- C[2kt+(j>>2)][j&3] * e_j  (in-lane!)
            U8 f0, f1;
            f0.u[0] = pk2(C[0][0] * lo16(e0.x), C[0][1] * hi16(e0.x));
            f0.u[1] = pk2(C[0][2] * lo16(e0.y), C[0][3] * hi16(e0.y));
            f0.u[2] = pk2(C[1][0] * lo16(e0.z), C[1][1] * hi16(e0.z));
            f0.u[3] = pk2(C[1][2] * lo16(e0.w), C[1][3] * hi16(e0.w));
            f1.u[0] = pk2(C[2][0] * lo16(e1.x), C[2][1] * hi16(e1.x));
            f1.u[1] = pk2(C[2][2] * lo16(e1.y), C[2][3] * hi16(e1.y));
            f1.u[2] = pk2(C[3][0] * lo16(e1.z), C[3][1] * hi16(e1.z));
            f1.u[3] = pk2(C[3][2] * lo16(e1.w), C[3][3] * hi16(e1.w));
            B0 = f0.v; B1 = f1.v;
        }
    }

    // logZ = log(sum_k beta[k][n] * A[k][EOS]) - total scale
    short8 Afin[2];
#pragma unroll
    for (int kt = 0; kt < 2; ++kt) {
        U8 f;
#pragma unroll
        for (int j = 0; j < 8; ++j)
            f.s[j] = (n == 0) ? f2bf(A[(kt * 32 + qA * 8 + j) * KT + EOS_T]) : (short)0;
        Afin[kt] = f.v;
    }
    f32x4 Cf = {0.f, 0.f, 0.f, 0.f};
    Cf = __builtin_amdgcn_mfma_f32_16x16x32_bf16(Afin[0], B0, Cf, 0, 0, 0);
    Cf = __builtin_amdgcn_mfma_f32_16x16x32_bf16(Afin[1], B1, Cf, 0, 0, 0);
    if (qA == 0)
        out[b0 + n] = logf(Cf[0]) - LOG_TOTAL_SCALE;
}

extern "C" void kernel_launch(void* const* d_in, const int* in_sizes, int n_in,
                              void* d_out, int out_size, void* d_ws, size_t ws_size,
                              hipStream_t stream) {
    const int*   words  = (const int*)d_in[0];     // [8192,126]
    const float* ThetaB = (const float*)d_in[1];   // [64,128]
    const float* WA     = (const float*)d_in[2];   // [64,64]
    const float* E      = (const float*)d_in[3];   // [50000,128]
    float* out = (float*)d_out;                    // [8192]

    char* ws = (char*)d_ws;
    unsigned short* btn_bf = (unsigned short*)(ws + BTN_OFF);
    float* A       = (float*)(ws + A_OFF);
    float* sumexp  = (float*)(ws + SUM_OFF);
    float* partial = (float*)(ws + PART_OFF);

    k_emit<<<NBLK, 256, 0, stream>>>(ThetaB, E, btn_bf, partial);
    k_sumA<<<KT, 256, 0, stream>>>(partial, WA, sumexp, A);
    k_fwd<<<8192 / 16, 64, 0, stream>>>(words, btn_bf, A, sumexp, out);
}

// Round 9
// 137.850 us; speedup vs baseline: 1.2605x; 1.1672x over previous
//
#include <hip/hip_runtime.h>
#include <hip/hip_bf16.h>
#include <math.h>

// HMM forward (logZ), K=64 tags, V=50000, D=128, BATCH=8192, L=126.
// Transposed MFMA recurrence: beta_next = (T'^T x beta) .* e, with the MFMA
// C-layout -> next-step B-layout transform done by pure in-lane register
// renaming (tag relabeling absorbed into the T'^T A-operand).
// r9: word indices staged in LDS (lgkmcnt domain) so the 6-deep emission
// gather ring is no longer serialized by a 2-deep vmcnt-domain index feed
// (r8: ~970 cyc/step, all stall on the in-order vmcnt wait).
//
// ws layout:
//   [0, 6,400,000)        btn_bf[v][k]  bf16  raw exp(logit)
//   [6,400,000, +16384)   A[i][j]       f32   softmax(WA, col BOS=-inf)+EPS
//   [6,416,384, +256)     sumexp[k]     f32
//   [6,416,640, +200704)  partial[k][784] f32 per-block column sums

#define KT 64
#define VV 50000
#define DD 128
#define BOS_T 62
#define EOS_T 63
#define LLEN 126
#define EPSF 1e-45f
#define SCALE_F 65536.0f
#define LOG_TOTAL_SCALE (2016.0f * 0.6931471805599453f)
#define NBLK 782          // k_emit grid
#define PBLK 784          // padded partial row

#define BTN_OFF   0
#define A_OFF     6400000
#define SUM_OFF   6416384
#define PART_OFF  6416640

typedef short short8 __attribute__((ext_vector_type(8)));
typedef float f32x4  __attribute__((ext_vector_type(4)));

union U8 { short8 v; unsigned u[4]; short s[8]; };

static __device__ inline unsigned short f2bf_u(float x) {
    __hip_bfloat16 h = __float2bfloat16(x);
    return *reinterpret_cast<unsigned short*>(&h);
}
static __device__ inline short f2bf(float x) { return (short)f2bf_u(x); }

#if __has_builtin(__builtin_amdgcn_cvt_pk_bf16_f32)
typedef __bf16 bf16x2 __attribute__((ext_vector_type(2)));
static __device__ inline unsigned pk2(float a, float b) {
    bf16x2 r = __builtin_amdgcn_cvt_pk_bf16_f32(a, b);
    return *reinterpret_cast<unsigned*>(&r);
}
#else
static __device__ inline unsigned pk2(float a, float b) {
    union { float f; unsigned u; } ua, ub;
    ua.f = a; ub.f = b;
    return ((ua.u + 0x8000u) >> 16) | ((ub.u + 0x8000u) & 0xFFFF0000u);
}
#endif
static __device__ inline float lo16(unsigned u) { union { unsigned i; float f; } c; c.i = u << 16;        return c.f; }
static __device__ inline float hi16(unsigned u) { union { unsigned i; float f; } c; c.i = u & 0xffff0000u; return c.f; }

// ---------------------------------------------------------------- btn_bf[v][k] = bf16(exp(E[v].ThetaB[k]))  (MFMA GEMM)
__global__ __launch_bounds__(256) void k_emit(const float* __restrict__ ThetaB,
                                              const float* __restrict__ E,
                                              unsigned short* __restrict__ btn_bf,
                                              float* __restrict__ partial) {
    __shared__ float red[4][KT];
    int t    = threadIdx.x;
    int lane = t & 63;
    int w    = t >> 6;
    int n    = lane & 15;
    int q    = lane >> 4;
    int v0   = (blockIdx.x * 4 + w) * 16;

    // E rows are the cold HBM traffic — issue early.
    int rowE = v0 + n; rowE = rowE < VV ? rowE : VV - 1;
    float4 ex[4][2];
#pragma unroll
    for (int kt = 0; kt < 4; ++kt) {
        const float* p = E + (size_t)rowE * DD + kt * 32 + q * 8;
        ex[kt][0] = *(const float4*)p;
        ex[kt][1] = *(const float4*)(p + 4);
    }

    short8 Bf[4][4];
#pragma unroll
    for (int kt = 0; kt < 4; ++kt)
#pragma unroll
        for (int nt = 0; nt < 4; ++nt) {
            const float* p = ThetaB + (nt * 16 + n) * DD + kt * 32 + q * 8;
            float4 x = *(const float4*)p;
            float4 y = *(const float4*)(p + 4);
            U8 f;
            f.u[0] = pk2(x.x, x.y); f.u[1] = pk2(x.z, x.w);
            f.u[2] = pk2(y.x, y.y); f.u[3] = pk2(y.z, y.w);
            Bf[kt][nt] = f.v;
        }

    short8 Ae[4];
#pragma unroll
    for (int kt = 0; kt < 4; ++kt) {
        U8 f;
        f.u[0] = pk2(ex[kt][0].x, ex[kt][0].y); f.u[1] = pk2(ex[kt][0].z, ex[kt][0].w);
        f.u[2] = pk2(ex[kt][1].x, ex[kt][1].y); f.u[3] = pk2(ex[kt][1].z, ex[kt][1].w);
        Ae[kt] = f.v;
    }

#pragma unroll
    for (int nt = 0; nt < 4; ++nt) {
        f32x4 C = {0.f, 0.f, 0.f, 0.f};
#pragma unroll
        for (int kt = 0; kt < 4; ++kt)
            C = __builtin_amdgcn_mfma_f32_16x16x32_bf16(Ae[kt], Bf[kt][nt], C, 0, 0, 0);
        float ps = 0.0f;
#pragma unroll
        for (int r = 0; r < 4; ++r) {
            int row = v0 + 4 * q + r;
            float e = __expf(C[r]);
            if (row < VV) {
                btn_bf[(size_t)row * KT + nt * 16 + n] = f2bf_u(e);
                ps += e;
            }
        }
        ps += __shfl_xor(ps, 16, 64);
        ps += __shfl_xor(ps, 32, 64);
        if (q == 0) red[w][nt * 16 + n] = ps;
    }
    __syncthreads();
    if (w == 0) {
        float s = red[0][lane] + red[1][lane] + red[2][lane] + red[3][lane];
        partial[lane * PBLK + blockIdx.x] = s;
    }
}

// ---------------------------------------------------------------- sumexp[k] = sum partial[k][:]; A row k = softmax(WA row k)
__global__ __launch_bounds__(256) void k_sumA(const float* __restrict__ partial,
                                              const float* __restrict__ WA,
                                              float* __restrict__ sumexp,
                                              float* __restrict__ A) {
    __shared__ float r[4];
    int k = blockIdx.x;
    int t = threadIdx.x;
    float s = 0.0f;
    for (int i = t; i < NBLK; i += 256) s += partial[k * PBLK + i];
#pragma unroll
    for (int off = 32; off > 0; off >>= 1) s += __shfl_xor(s, off, 64);
    if ((t & 63) == 0) r[t >> 6] = s;
    __syncthreads();
    if (t == 0) sumexp[k] = r[0] + r[1] + r[2] + r[3];
    if (t < 64) {
        float wv = WA[k * KT + t];
        float e = (t == BOS_T) ? 0.0f : __expf(wv);
        float se = e;
#pragma unroll
        for (int off = 32; off > 0; off >>= 1) se += __shfl_xor(se, off, 64);
        A[k * KT + t] = e / se + EPSF;
    }
}

// ---------------------------------------------------------------- forward scan: 1 wave = 16 sentences, zero-LDS-transform MFMA
__global__ __launch_bounds__(64) void k_fwd(const int* __restrict__ words,
                                            const unsigned short* __restrict__ btn_bf,
                                            const float* __restrict__ A,
                                            const float* __restrict__ sumexp,
                                            float* __restrict__ out) {
    __shared__ int shw[16 * LLEN];   // 8064 B: this block's word indices
    int lane = threadIdx.x & 63;
    int n    = lane & 15;     // sentence col (B/C side); row m (A side)
    int qA   = lane >> 4;
    int b0   = blockIdx.x * 16;

    // Stage word indices: rows b0..b0+15 are CONTIGUOUS in words (8064 B).
    // Index reads below become ds_read (lgkmcnt domain) so the emission
    // gather ring's vmcnt waits never chain on an index load (r8 bug).
    {
        const uint4* src = (const uint4*)(words + (size_t)b0 * LLEN);
        uint4* dst = (uint4*)shw;
#pragma unroll
        for (int i = 0; i < 8; ++i) {
            int idx = lane + 64 * i;
            if (idx < (16 * LLEN) / 4) dst[idx] = src[idx];
        }
    }

    // A-operand frags of scaled T'^T; tag at C-position (mt, m):
    //   tagn = 32*(mt>>1) + 8*(m>>2) + 4*(mt&1) + (m&3)
    short8 Af[2][4];
#pragma unroll
    for (int mt = 0; mt < 4; ++mt) {
        int tagn = 32 * (mt >> 1) + 8 * (n >> 2) + 4 * (mt & 1) + (n & 3);
        float s = sumexp[tagn];
        float rsn = (tagn == BOS_T || tagn == EOS_T) ? 0.0f : (SCALE_F / s);
#pragma unroll
        for (int kt = 0; kt < 2; ++kt) {
            U8 f;
#pragma unroll
            for (int j = 0; j < 8; ++j)
                f.s[j] = f2bf(A[(kt * 32 + qA * 8 + j) * KT + tagn] * rsn);
            Af[kt][mt] = f.v;
        }
    }

    // beta_0 one-hot at tag 62 = B-position (kt=1, q=3, j=6)
    short8 B0, B1;
    {
        U8 z; z.u[0] = z.u[1] = z.u[2] = z.u[3] = 0;
        B0 = z.v;
        U8 o; o.u[0] = o.u[1] = o.u[2] = o.u[3] = 0;
        if (qA == 3) o.s[6] = (short)0x3F80;   // bf16(1.0)
        B1 = o.v;
    }

    const int* wrow = shw + n * LLEN;   // LDS

    // 6-deep emission prefetch ring (register-renamed by full unroll)
    uint4 ep0[6], ep1[6];
#pragma unroll
    for (int d = 0; d < 6; ++d) {
        int wd = wrow[d];
        ep0[d] = *(const uint4*)(btn_bf + (size_t)wd * KT + qA * 8);
        ep1[d] = *(const uint4*)(btn_bf + (size_t)wd * KT + 32 + qA * 8);
    }
    int w1 = wrow[6], w2 = wrow[7];   // 2-deep LDS index pipeline

    for (int l6 = 0; l6 < LLEN; l6 += 6) {
#pragma unroll
        for (int u = 0; u < 6; ++u) {
            int g = l6 + u;
            uint4 e0 = ep0[u], e1 = ep1[u];
            // refill slot u with step g+6's emission row; index from LDS
            {
                int wg = w1; w1 = w2;
                int wi = g + 8; wi = wi < LLEN ? wi : LLEN - 1;
                w2 = wrow[wi];
                ep0[u] = *(const uint4*)(btn_bf + (size_t)wg * KT + qA * 8);
                ep1[u] = *(const uint4*)(btn_bf + (size_t)wg * KT + 32 + qA * 8);
            }
            // C[mt] = Af[0][mt] x B0 + Af[1][mt] x B1
            f32x4 C[4];
#pragma unroll
            for (int mt = 0; mt < 4; ++mt) {
                f32x4 acc = {0.f, 0.f, 0.f, 0.f};
                acc = __builtin_amdgcn_mfma_f32_16x16x32_bf16(Af[0][mt], B0, acc, 0, 0, 0);
                acc = __builtin_amdgcn_mfma_f32_16x16x32_bf16(Af[1][mt], B1, acc, 0, 0, 0);
                C[mt] = acc;
            }
            // next B-frags: kt slot j <- C[2kt+(j>>2)][j&3] * e_j  (in-lane!)
            U8 f0, f1;
            f0.u[0] = pk2(C[0][0] * lo16(e0.x), C[0][1] * hi16(e0.x));
            f0.u[1] = pk2(C[0][2] * lo16(e0.y), C[0][3] * hi16(e0.y));
            f0.u[2] = pk2(C[1][0] * lo16(e0.z), C[1][1] * hi16(e0.z));
            f0.u[3] = pk2(C[1][2] * lo16(e0.w), C[1][3] * hi16(e0.w));
            f1.u[0] = pk2(C[2][0] * lo16(e1.x), C[2][1] * hi16(e1.x));
            f1.u[1] = pk2(C[2][2] * lo16(e1.y), C[2][3] * hi16(e1.y));
            f1.u[2] = pk2(C[3][0] * lo16(e1.z), C[3][1] * hi16(e1.z));
            f1.u[3] = pk2(C[3][2] * lo16(e1.w), C[3][3] * hi16(e1.w));
            B0 = f0.v; B1 = f1.v;
        }
    }

    // logZ = log(sum_k beta[k][n] * A[k][EOS]) - total scale
    short8 Afin[2];
#pragma unroll
    for (int kt = 0; kt < 2; ++kt) {
        U8 f;
#pragma unroll
        for (int j = 0; j < 8; ++j)
            f.s[j] = (n == 0) ? f2bf(A[(kt * 32 + qA * 8 + j) * KT + EOS_T]) : (short)0;
        Afin[kt] = f.v;
    }
    f32x4 Cf = {0.f, 0.f, 0.f, 0.f};
    Cf = __builtin_amdgcn_mfma_f32_16x16x32_bf16(Afin[0], B0, Cf, 0, 0, 0);
    Cf = __builtin_amdgcn_mfma_f32_16x16x32_bf16(Afin[1], B1, Cf, 0, 0, 0);
    if (qA == 0)
        out[b0 + n] = logf(Cf[0]) - LOG_TOTAL_SCALE;
}

extern "C" void kernel_launch(void* const* d_in, const int* in_sizes, int n_in,
                              void* d_out, int out_size, void* d_ws, size_t ws_size,
                              hipStream_t stream) {
    const int*   words  = (const int*)d_in[0];     // [8192,126]
    const float* ThetaB = (const float*)d_in[1];   // [64,128]
    const float* WA     = (const float*)d_in[2];   // [64,64]
    const float* E      = (const float*)d_in[3];   // [50000,128]
    float* out = (float*)d_out;                    // [8192]

    char* ws = (char*)d_ws;
    unsigned short* btn_bf = (unsigned short*)(ws + BTN_OFF);
    float* A       = (float*)(ws + A_OFF);
    float* sumexp  = (float*)(ws + SUM_OFF);
    float* partial = (float*)(ws + PART_OFF);

    k_emit<<<NBLK, 256, 0, stream>>>(ThetaB, E, btn_bf, partial);
    k_sumA<<<KT, 256, 0, stream>>>(partial, WA, sumexp, A);
    k_fwd<<<8192 / 16, 64, 0, stream>>>(words, btn_bf, A, sumexp, out);
}